// Round 1
// baseline (3748.117 us; speedup 1.0000x reference)
//
#include <hip/hip_runtime.h>

#define N_NODES 100000
#define N_EDGES 600000
#define NODE_DIM 64
#define EDGE_DIM 32
#define HID 128
#define OUT_DIM 24
#define FEAT (2 * HID + EDGE_DIM)  // 288

// -------- lin1: h[n][t] = b[t] + sum_k x[n][k] * w[k][t] --------
__global__ __launch_bounds__(256) void lin1_kernel(
    const float* __restrict__ x, const float* __restrict__ w,
    const float* __restrict__ b, float* __restrict__ h) {
  int idx = blockIdx.x * blockDim.x + threadIdx.x;
  if (idx >= N_NODES * HID) return;
  int n = idx >> 7;
  int t = idx & 127;
  float acc = b[t];
  const float* xr = x + n * NODE_DIM;
#pragma unroll
  for (int k = 0; k < NODE_DIM; ++k)
    acc = fmaf(xr[k], w[k * HID + t], acc);
  h[idx] = acc;
}

// -------- edge message: m = relu(h[src] + edge_attr@ew + eb); atomicAdd to agg[dst]
__global__ __launch_bounds__(256) void edge_msg_kernel(
    const float* __restrict__ h, const float* __restrict__ ea,
    const int* __restrict__ src, const int* __restrict__ dst,
    const float* __restrict__ ew, const float* __restrict__ eb,
    float* __restrict__ agg) {
  int idx = blockIdx.x * blockDim.x + threadIdx.x;
  if (idx >= N_EDGES * HID) return;
  int e = idx >> 7;
  int t = idx & 127;
  float acc = eb[t];
  const float* ear = ea + e * EDGE_DIM;  // wave-broadcast reads
#pragma unroll
  for (int k = 0; k < EDGE_DIM; ++k)
    acc = fmaf(ear[k], ew[k * HID + t], acc);
  int s = src[e];
  float m = h[s * HID + t] + acc;
  m = m > 0.f ? m : 0.f;
  int d = dst[e];
  atomicAdd(&agg[d * HID + t], m);
}

// -------- node MLP: hout = relu(relu((h+agg)@w1+b1)@w2+b2), in-place into agg OK
#define MLP_NODES 16
__global__ __launch_bounds__(128) void mlp_kernel(
    const float* __restrict__ h, const float* __restrict__ agg,
    const float* __restrict__ w1, const float* __restrict__ b1,
    const float* __restrict__ w2, const float* __restrict__ b2,
    float* __restrict__ hout) {
  __shared__ float zs[MLP_NODES * HID];   // 8 KB
  __shared__ float t1[MLP_NODES * HID];   // 8 KB
  int t = threadIdx.x;
  int base = blockIdx.x * MLP_NODES;
  for (int i = t; i < MLP_NODES * HID; i += 128) {
    int g = base * HID + i;
    zs[i] = h[g] + agg[g];
  }
  __syncthreads();
  float acc[MLP_NODES];
#pragma unroll
  for (int n = 0; n < MLP_NODES; ++n) acc[n] = b1[t];
  for (int k = 0; k < HID; ++k) {
    float wv = w1[k * HID + t];
#pragma unroll
    for (int n = 0; n < MLP_NODES; ++n)
      acc[n] = fmaf(zs[n * HID + k], wv, acc[n]);  // zs: LDS broadcast (free)
  }
#pragma unroll
  for (int n = 0; n < MLP_NODES; ++n)
    t1[n * HID + t] = acc[n] > 0.f ? acc[n] : 0.f;
  __syncthreads();
#pragma unroll
  for (int n = 0; n < MLP_NODES; ++n) acc[n] = b2[t];
  for (int k = 0; k < HID; ++k) {
    float wv = w2[k * HID + t];
#pragma unroll
    for (int n = 0; n < MLP_NODES; ++n)
      acc[n] = fmaf(t1[n * HID + k], wv, acc[n]);
  }
#pragma unroll
  for (int n = 0; n < MLP_NODES; ++n) {
    float v = acc[n] > 0.f ? acc[n] : 0.f;
    hout[(base + n) * HID + t] = v;
  }
}

// -------- classifier: out = relu(concat(h[src],h[dst],ea)@w1+b1)@w2+b2
#define CLS_EDGES 16
__global__ __launch_bounds__(128) void cls_kernel(
    const float* __restrict__ h, const float* __restrict__ ea,
    const int* __restrict__ src, const int* __restrict__ dst,
    const float* __restrict__ w1, const float* __restrict__ b1,
    const float* __restrict__ w2, const float* __restrict__ b2,
    float* __restrict__ out) {
  __shared__ float fs[CLS_EDGES * FEAT];  // 18 KB
  __shared__ float t1[CLS_EDGES * HID];   // 8 KB
  int t = threadIdx.x;
  int ebase = blockIdx.x * CLS_EDGES;
#pragma unroll
  for (int n = 0; n < CLS_EDGES; ++n) {
    int e = ebase + n;
    int s = src[e], d = dst[e];  // uniform across block -> broadcast
    fs[n * FEAT + t] = h[s * HID + t];
    fs[n * FEAT + HID + t] = h[d * HID + t];
    if (t < EDGE_DIM) fs[n * FEAT + 2 * HID + t] = ea[e * EDGE_DIM + t];
  }
  __syncthreads();
  float acc[CLS_EDGES];
#pragma unroll
  for (int n = 0; n < CLS_EDGES; ++n) acc[n] = b1[t];
  for (int k = 0; k < FEAT; ++k) {
    float wv = w1[k * HID + t];
#pragma unroll
    for (int n = 0; n < CLS_EDGES; ++n)
      acc[n] = fmaf(fs[n * FEAT + k], wv, acc[n]);
  }
#pragma unroll
  for (int n = 0; n < CLS_EDGES; ++n)
    t1[n * HID + t] = acc[n] > 0.f ? acc[n] : 0.f;
  __syncthreads();
  for (int oi = t; oi < CLS_EDGES * OUT_DIM; oi += 128) {
    int n = oi / OUT_DIM, o = oi % OUT_DIM;
    float a2 = b2[o];
    for (int k = 0; k < HID; ++k)
      a2 = fmaf(t1[n * HID + k], w2[k * OUT_DIM + o], a2);
    out[(ebase + n) * OUT_DIM + o] = a2;
  }
}

extern "C" void kernel_launch(void* const* d_in, const int* in_sizes, int n_in,
                              void* d_out, int out_size, void* d_ws, size_t ws_size,
                              hipStream_t stream) {
  const float* x = (const float*)d_in[0];
  const int* ei = (const int*)d_in[1];
  const float* ea = (const float*)d_in[2];
  const float* lin1_w = (const float*)d_in[3];
  const float* lin1_b = (const float*)d_in[4];
  const int* src = ei;
  const int* dst = ei + N_EDGES;

  const size_t NH = (size_t)N_NODES * HID;
  float* bufA = (float*)d_ws;        // 51.2 MB
  float* bufB = bufA + NH;           // 51.2 MB  (total 102.4 MB of ws)

  lin1_kernel<<<(N_NODES * HID + 255) / 256, 256, 0, stream>>>(x, lin1_w, lin1_b, bufA);

  float* hcur = bufA;
  float* aux = bufB;
  for (int c = 0; c < 3; ++c) {
    const float* ew = (const float*)d_in[5 + c * 6 + 0];
    const float* eb = (const float*)d_in[5 + c * 6 + 1];
    const float* w1 = (const float*)d_in[5 + c * 6 + 2];
    const float* b1 = (const float*)d_in[5 + c * 6 + 3];
    const float* w2 = (const float*)d_in[5 + c * 6 + 4];
    const float* b2 = (const float*)d_in[5 + c * 6 + 5];
    hipMemsetAsync(aux, 0, NH * sizeof(float), stream);
    edge_msg_kernel<<<(N_EDGES * HID + 255) / 256, 256, 0, stream>>>(
        hcur, ea, src, dst, ew, eb, aux);
    // MLP writes in-place into aux (each block reads only its own row-tile first)
    mlp_kernel<<<N_NODES / MLP_NODES, 128, 0, stream>>>(
        hcur, aux, w1, b1, w2, b2, aux);
    float* tmp = hcur; hcur = aux; aux = tmp;
  }

  const float* cw1 = (const float*)d_in[23];
  const float* cb1 = (const float*)d_in[24];
  const float* cw2 = (const float*)d_in[25];
  const float* cb2 = (const float*)d_in[26];
  cls_kernel<<<N_EDGES / CLS_EDGES, 128, 0, stream>>>(
      hcur, ea, src, dst, cw1, cb1, cw2, cb2, (float*)d_out);
}

// Round 2
// 2831.828 us; speedup vs baseline: 1.3236x; 1.3236x over previous
//
#include <hip/hip_runtime.h>

#define N_NODES 100000
#define N_EDGES 600000
#define NODE_DIM 64
#define EDGE_DIM 32
#define HID 128
#define OUT_DIM 24

// ================= lin1: h = x @ w + b  (K=64) =================
__global__ __launch_bounds__(256) void lin1_kernel(
    const float* __restrict__ x, const float* __restrict__ w,
    const float* __restrict__ b, float* __restrict__ h) {
  __shared__ float4 smem4[3072];           // 48 KB
  float* sA = (float*)smem4;               // A_t[k][m], 64x64
  float* sB = (float*)smem4 + 4096;        // B[k][n],  64x128
  int tid = threadIdx.x;
  int tn = tid & 31, tm = tid >> 5;        // n0=tn*4, m0=tm*8
  int mbase = blockIdx.x * 64;

  for (int i = tid; i < 1024; i += 256) {  // stage A transposed
    int m = i & 63, k4 = (i >> 6) << 2;
    int row = mbase + m; if (row >= N_NODES) row = N_NODES - 1;
    float4 v = *(const float4*)(x + (size_t)row * NODE_DIM + k4);
    sA[(k4 + 0) * 64 + m] = v.x; sA[(k4 + 1) * 64 + m] = v.y;
    sA[(k4 + 2) * 64 + m] = v.z; sA[(k4 + 3) * 64 + m] = v.w;
  }
  for (int i = tid; i < 2048; i += 256)    // stage B (64x128)
    *(float4*)&sB[i * 4] = ((const float4*)w)[i];
  __syncthreads();

  float acc[8][4] = {};
#pragma unroll 8
  for (int k = 0; k < 64; ++k) {
    float4 a0 = *(float4*)&sA[k * 64 + tm * 8];
    float4 a1 = *(float4*)&sA[k * 64 + tm * 8 + 4];
    float4 bv = *(float4*)&sB[k * 128 + tn * 4];
    float av[8] = {a0.x, a0.y, a0.z, a0.w, a1.x, a1.y, a1.z, a1.w};
    float bb[4] = {bv.x, bv.y, bv.z, bv.w};
#pragma unroll
    for (int i = 0; i < 8; ++i)
#pragma unroll
      for (int j = 0; j < 4; ++j) acc[i][j] = fmaf(av[i], bb[j], acc[i][j]);
  }
  float4 bv = *(const float4*)(b + tn * 4);
#pragma unroll
  for (int i = 0; i < 8; ++i) {
    int row = mbase + tm * 8 + i;
    if (row < N_NODES) {
      float4 o = {acc[i][0] + bv.x, acc[i][1] + bv.y, acc[i][2] + bv.z, acc[i][3] + bv.w};
      *(float4*)(h + (size_t)row * HID + tn * 4) = o;
    }
  }
}

// ======== edge message: one wave per edge, ew column pair in VGPRs ========
__global__ __launch_bounds__(256) void edge_msg_kernel(
    const float* __restrict__ h, const float* __restrict__ ea,
    const int* __restrict__ src, const int* __restrict__ dst,
    const float* __restrict__ ew, const float* __restrict__ eb,
    float* __restrict__ agg) {
  int tid = threadIdx.x;
  int lane = tid & 63;
  int wid = __builtin_amdgcn_readfirstlane(tid >> 6);  // wave id, uniform
  float2 ewreg[32];
#pragma unroll
  for (int k = 0; k < 32; ++k)
    ewreg[k] = *(const float2*)(ew + k * HID + lane * 2);
  float2 ebv = *(const float2*)(eb + lane * 2);
  int e0 = blockIdx.x * 256 + wid * 64;
  for (int i = 0; i < 64; ++i) {
    int e = e0 + i;
    if (e >= N_EDGES) break;
    int s = src[e], d = dst[e];          // uniform -> scalar loads
    float2 acc = ebv;
#pragma unroll
    for (int k = 0; k < 32; ++k) {
      float a = ea[(size_t)e * EDGE_DIM + k];  // uniform address
      acc.x = fmaf(a, ewreg[k].x, acc.x);
      acc.y = fmaf(a, ewreg[k].y, acc.y);
    }
    float2 hv = *(const float2*)(h + (size_t)s * HID + lane * 2);
    float m0 = fmaxf(acc.x + hv.x, 0.f);
    float m1 = fmaxf(acc.y + hv.y, 0.f);
    float* ap = agg + (size_t)d * HID + lane * 2;
    atomicAdd(ap, m0);
    atomicAdd(ap + 1, m1);
  }
}

// ======== node MLP: hout = relu(relu((h+agg)@w1+b1)@w2+b2)  ========
__global__ __launch_bounds__(256) void mlp_kernel(
    const float* __restrict__ h, const float* __restrict__ agg,
    const float* __restrict__ w1, const float* __restrict__ b1,
    const float* __restrict__ w2, const float* __restrict__ b2,
    float* __restrict__ hout) {
  __shared__ float4 smem4[3200];           // 51.2 KB
  float* sB = (float*)smem4;               // [0,4096)   B chunk 32x128
  float* sA = (float*)smem4 + 4096;        // [4096,6144) A_t chunk 32x64
  float* t1 = (float*)smem4 + 4096;        // [4096,12800) t1_t[k][m] 128x68 (overlaps sA; written after GEMM1)
  int tid = threadIdx.x;
  int tn = tid & 31, tm = tid >> 5;
  int mbase = blockIdx.x * 64;

  float acc[8][4] = {};
  for (int kc = 0; kc < 4; ++kc) {
    __syncthreads();
    for (int i = tid; i < 512; i += 256) {
      int m = i & 63, k4 = (i >> 6) << 2;
      int row = mbase + m; if (row >= N_NODES) row = N_NODES - 1;
      size_t g = (size_t)row * HID + kc * 32 + k4;
      float4 hv = *(const float4*)(h + g);
      float4 av = *(const float4*)(agg + g);
      sA[(k4 + 0) * 64 + m] = hv.x + av.x; sA[(k4 + 1) * 64 + m] = hv.y + av.y;
      sA[(k4 + 2) * 64 + m] = hv.z + av.z; sA[(k4 + 3) * 64 + m] = hv.w + av.w;
    }
    for (int i = tid; i < 1024; i += 256)
      *(float4*)&sB[i * 4] = *(const float4*)(w1 + (size_t)kc * 32 * HID + i * 4);
    __syncthreads();
#pragma unroll
    for (int k = 0; k < 32; ++k) {
      float4 a0 = *(float4*)&sA[k * 64 + tm * 8];
      float4 a1 = *(float4*)&sA[k * 64 + tm * 8 + 4];
      float4 bv = *(float4*)&sB[k * 128 + tn * 4];
      float av[8] = {a0.x, a0.y, a0.z, a0.w, a1.x, a1.y, a1.z, a1.w};
      float bb[4] = {bv.x, bv.y, bv.z, bv.w};
#pragma unroll
      for (int i = 0; i < 8; ++i)
#pragma unroll
        for (int j = 0; j < 4; ++j) acc[i][j] = fmaf(av[i], bb[j], acc[i][j]);
    }
  }
  __syncthreads();  // all inner reads done before t1 overwrites sA
  float4 b1v = *(const float4*)(b1 + tn * 4);
  float bb1[4] = {b1v.x, b1v.y, b1v.z, b1v.w};
#pragma unroll
  for (int i = 0; i < 8; ++i)
#pragma unroll
    for (int j = 0; j < 4; ++j) {
      float v = fmaxf(acc[i][j] + bb1[j], 0.f);
      t1[(tn * 4 + j) * 68 + tm * 8 + i] = v;   // transposed, pad 68
    }

  float acc2[8][4] = {};
  for (int kc = 0; kc < 4; ++kc) {
    __syncthreads();
    for (int i = tid; i < 1024; i += 256)
      *(float4*)&sB[i * 4] = *(const float4*)(w2 + (size_t)kc * 32 * HID + i * 4);
    __syncthreads();
#pragma unroll
    for (int k = 0; k < 32; ++k) {
      int kk = kc * 32 + k;
      float4 a0 = *(float4*)&t1[kk * 68 + tm * 8];
      float4 a1 = *(float4*)&t1[kk * 68 + tm * 8 + 4];
      float4 bv = *(float4*)&sB[k * 128 + tn * 4];
      float av[8] = {a0.x, a0.y, a0.z, a0.w, a1.x, a1.y, a1.z, a1.w};
      float bb[4] = {bv.x, bv.y, bv.z, bv.w};
#pragma unroll
      for (int i = 0; i < 8; ++i)
#pragma unroll
        for (int j = 0; j < 4; ++j) acc2[i][j] = fmaf(av[i], bb[j], acc2[i][j]);
    }
  }
  float4 b2v = *(const float4*)(b2 + tn * 4);
  float bb2[4] = {b2v.x, b2v.y, b2v.z, b2v.w};
#pragma unroll
  for (int i = 0; i < 8; ++i) {
    int row = mbase + tm * 8 + i;
    if (row < N_NODES) {
      float4 o = {fmaxf(acc2[i][0] + bb2[0], 0.f), fmaxf(acc2[i][1] + bb2[1], 0.f),
                  fmaxf(acc2[i][2] + bb2[2], 0.f), fmaxf(acc2[i][3] + bb2[3], 0.f)};
      *(float4*)(hout + (size_t)row * HID + tn * 4) = o;
    }
  }
}

// ======== classifier: out = relu(concat(h[src],h[dst],ea)@w1+b1)@w2+b2 ========
__global__ __launch_bounds__(256) void cls_kernel(
    const float* __restrict__ h, const float* __restrict__ ea,
    const int* __restrict__ src, const int* __restrict__ dst,
    const float* __restrict__ w1, const float* __restrict__ b1,
    const float* __restrict__ w2, const float* __restrict__ b2,
    float* __restrict__ out) {
  __shared__ float4 smem4[2832];           // 45.3 KB
  float* sB  = (float*)smem4;              // [0,4096)    w1 chunk 32x128
  float* sA  = (float*)smem4 + 4096;       // [4096,6144) A_t chunk 32x64
  float* t1  = (float*)smem4;              // [0,8256)    t1[m][k] 64x129 (after GEMM1)
  float* w2s = (float*)smem4 + 8256;       // [8256,11328) w2 128x24
  __shared__ int sidx[128];
  int tid = threadIdx.x;
  int tn = tid & 31, tm = tid >> 5;
  int ebase = blockIdx.x * 64;             // 9375 blocks, exact

  for (int i = tid; i < 768; i += 256)
    *(float4*)&w2s[i * 4] = ((const float4*)w2)[i];
  if (tid < 64) sidx[tid] = src[ebase + tid];
  else if (tid < 128) sidx[tid] = dst[ebase + tid - 64];
  __syncthreads();

  float acc[8][4] = {};
  for (int c = 0; c < 9; ++c) {
    __syncthreads();
    for (int i = tid; i < 512; i += 256) {
      int e2 = i & 63, k4 = (i >> 6) << 2;
      const float* rp;
      if (c < 4)      rp = h + (size_t)sidx[e2] * HID + c * 32 + k4;
      else if (c < 8) rp = h + (size_t)sidx[64 + e2] * HID + (c - 4) * 32 + k4;
      else            rp = ea + (size_t)(ebase + e2) * EDGE_DIM + k4;
      float4 v = *(const float4*)rp;
      sA[(k4 + 0) * 64 + e2] = v.x; sA[(k4 + 1) * 64 + e2] = v.y;
      sA[(k4 + 2) * 64 + e2] = v.z; sA[(k4 + 3) * 64 + e2] = v.w;
    }
    for (int i = tid; i < 1024; i += 256)
      *(float4*)&sB[i * 4] = *(const float4*)(w1 + (size_t)c * 32 * HID + i * 4);
    __syncthreads();
#pragma unroll
    for (int k = 0; k < 32; ++k) {
      float4 a0 = *(float4*)&sA[k * 64 + tm * 8];
      float4 a1 = *(float4*)&sA[k * 64 + tm * 8 + 4];
      float4 bv = *(float4*)&sB[k * 128 + tn * 4];
      float av[8] = {a0.x, a0.y, a0.z, a0.w, a1.x, a1.y, a1.z, a1.w};
      float bb[4] = {bv.x, bv.y, bv.z, bv.w};
#pragma unroll
      for (int i = 0; i < 8; ++i)
#pragma unroll
        for (int j = 0; j < 4; ++j) acc[i][j] = fmaf(av[i], bb[j], acc[i][j]);
    }
  }
  __syncthreads();  // all inner reads done before t1 overwrites sA/sB
  float4 b1v = *(const float4*)(b1 + tn * 4);
  float bb1[4] = {b1v.x, b1v.y, b1v.z, b1v.w};
#pragma unroll
  for (int i = 0; i < 8; ++i)
#pragma unroll
    for (int j = 0; j < 4; ++j)
      t1[(tm * 8 + i) * 129 + tn * 4 + j] = fmaxf(acc[i][j] + bb1[j], 0.f);
  __syncthreads();

  // GEMM2: 64x24, K=128. thread -> (m2 = tid&63, og = tid>>6), 6 outs each
  int m2 = tid & 63, og = tid >> 6;
  float acc2[6];
#pragma unroll
  for (int j = 0; j < 6; ++j) acc2[j] = b2[og * 6 + j];
#pragma unroll 4
  for (int k = 0; k < 128; ++k) {
    float a = t1[m2 * 129 + k];
#pragma unroll
    for (int j = 0; j < 6; ++j)
      acc2[j] = fmaf(a, w2s[k * OUT_DIM + og * 6 + j], acc2[j]);
  }
#pragma unroll
  for (int j = 0; j < 6; ++j)
    out[(size_t)(ebase + m2) * OUT_DIM + og * 6 + j] = acc2[j];
}

extern "C" void kernel_launch(void* const* d_in, const int* in_sizes, int n_in,
                              void* d_out, int out_size, void* d_ws, size_t ws_size,
                              hipStream_t stream) {
  const float* x = (const float*)d_in[0];
  const int* ei = (const int*)d_in[1];
  const float* ea = (const float*)d_in[2];
  const float* lin1_w = (const float*)d_in[3];
  const float* lin1_b = (const float*)d_in[4];
  const int* src = ei;
  const int* dst = ei + N_EDGES;

  const size_t NH = (size_t)N_NODES * HID;
  float* bufA = (float*)d_ws;
  float* bufB = bufA + NH;

  lin1_kernel<<<(N_NODES + 63) / 64, 256, 0, stream>>>(x, lin1_w, lin1_b, bufA);

  float* hcur = bufA;
  float* aux = bufB;
  for (int c = 0; c < 3; ++c) {
    const float* ew = (const float*)d_in[5 + c * 6 + 0];
    const float* eb = (const float*)d_in[5 + c * 6 + 1];
    const float* w1 = (const float*)d_in[5 + c * 6 + 2];
    const float* b1 = (const float*)d_in[5 + c * 6 + 3];
    const float* w2 = (const float*)d_in[5 + c * 6 + 4];
    const float* b2 = (const float*)d_in[5 + c * 6 + 5];
    hipMemsetAsync(aux, 0, NH * sizeof(float), stream);
    edge_msg_kernel<<<(N_EDGES + 255) / 256, 256, 0, stream>>>(
        hcur, ea, src, dst, ew, eb, aux);
    mlp_kernel<<<(N_NODES + 63) / 64, 256, 0, stream>>>(
        hcur, aux, w1, b1, w2, b2, aux);
    float* tmp = hcur; hcur = aux; aux = tmp;
  }

  const float* cw1 = (const float*)d_in[23];
  const float* cb1 = (const float*)d_in[24];
  const float* cw2 = (const float*)d_in[25];
  const float* cb2 = (const float*)d_in[26];
  cls_kernel<<<N_EDGES / 64, 256, 0, stream>>>(
      hcur, ea, src, dst, cw1, cb1, cw2, cb2, (float*)d_out);
}

// Round 3
// 2026.276 us; speedup vs baseline: 1.8498x; 1.3976x over previous
//
#include <hip/hip_runtime.h>

#define N_NODES 100000
#define N_EDGES 600000
#define NODE_DIM 64
#define EDGE_DIM 32
#define HID 128
#define OUT_DIM 24

typedef short short8 __attribute__((ext_vector_type(8)));
typedef short short4v __attribute__((ext_vector_type(4)));
typedef float f32x4 __attribute__((ext_vector_type(4)));

#define MFMA16(a, b, c) __builtin_amdgcn_mfma_f32_16x16x32_bf16(a, b, c, 0, 0, 0)

__device__ inline unsigned short f2bf(float f) {
  unsigned u = __float_as_uint(f);
  u += 0x7FFFu + ((u >> 16) & 1u);
  return (unsigned short)(u >> 16);
}
__device__ inline float bf2f(unsigned short b) {
  return __uint_as_float(((unsigned)b) << 16);
}

// ---- prepped weight region layout (ushort units) ----
#define OFF_CW1T 0                       // cls w1^T bf16 [128][288]
#define OFF_CW2T 36864                   // cls w2^T bf16 [32 pad][128]
#define OFF_LAYER(c) (40960 + (c)*65536) // per conv: w1t_hi,w1t_lo,w2t_hi,w2t_lo each [128][128]
#define W_TOTAL 237568

__global__ __launch_bounds__(256) void prep_weights(
    const float* __restrict__ cw1, const float* __restrict__ cw2,
    const float* __restrict__ l0w1, const float* __restrict__ l0w2,
    const float* __restrict__ l1w1, const float* __restrict__ l1w2,
    const float* __restrict__ l2w1, const float* __restrict__ l2w2,
    unsigned short* __restrict__ wb) {
  int i = blockIdx.x * 256 + threadIdx.x;
  if (i < 36864) {                       // cls w1t[n][k] = cw1[k][n]
    int n = i / 288, k = i % 288;
    wb[OFF_CW1T + i] = f2bf(cw1[k * 128 + n]);
  }
  int j = i - 36864;
  if (j >= 0 && j < 4096) {              // cls w2t[n][k], n padded to 32
    int n = j / 128, k = j % 128;
    wb[OFF_CW2T + j] = f2bf(n < 24 ? cw2[k * 24 + n] : 0.f);
  }
  int t = i - 40960;
  if (t >= 0 && t < 3 * 32768) {         // conv layers, split hi/lo
    int c = t / 32768, u = t % 32768;
    const float* w = (u < 16384) ? (c == 0 ? l0w1 : c == 1 ? l1w1 : l2w1)
                                 : (c == 0 ? l0w2 : c == 1 ? l1w2 : l2w2);
    int v = u & 16383;
    int n = v >> 7, k = v & 127;
    float val = w[k * 128 + n];
    unsigned short hi = f2bf(val);
    unsigned short lo = f2bf(val - bf2f(hi));
    int base = OFF_LAYER(c) + (u < 16384 ? 0 : 32768);
    wb[base + v] = hi;
    wb[base + 16384 + v] = lo;
  }
}

// ================= lin1: h = x @ w + b  (K=64, fp32) =================
__global__ __launch_bounds__(256) void lin1_kernel(
    const float* __restrict__ x, const float* __restrict__ w,
    const float* __restrict__ b, float* __restrict__ h) {
  __shared__ float4 smem4[3072];
  float* sA = (float*)smem4;
  float* sB = (float*)smem4 + 4096;
  int tid = threadIdx.x;
  int tn = tid & 31, tm = tid >> 5;
  int mbase = blockIdx.x * 64;

  for (int i = tid; i < 1024; i += 256) {
    int m = i & 63, k4 = (i >> 6) << 2;
    int row = mbase + m; if (row >= N_NODES) row = N_NODES - 1;
    float4 v = *(const float4*)(x + (size_t)row * NODE_DIM + k4);
    sA[(k4 + 0) * 64 + m] = v.x; sA[(k4 + 1) * 64 + m] = v.y;
    sA[(k4 + 2) * 64 + m] = v.z; sA[(k4 + 3) * 64 + m] = v.w;
  }
  for (int i = tid; i < 2048; i += 256)
    *(float4*)&sB[i * 4] = ((const float4*)w)[i];
  __syncthreads();

  float acc[8][4] = {};
#pragma unroll 8
  for (int k = 0; k < 64; ++k) {
    float4 a0 = *(float4*)&sA[k * 64 + tm * 8];
    float4 a1 = *(float4*)&sA[k * 64 + tm * 8 + 4];
    float4 bv = *(float4*)&sB[k * 128 + tn * 4];
    float av[8] = {a0.x, a0.y, a0.z, a0.w, a1.x, a1.y, a1.z, a1.w};
    float bb[4] = {bv.x, bv.y, bv.z, bv.w};
#pragma unroll
    for (int i = 0; i < 8; ++i)
#pragma unroll
      for (int jj = 0; jj < 4; ++jj) acc[i][jj] = fmaf(av[i], bb[jj], acc[i][jj]);
  }
  float4 bv = *(const float4*)(b + tn * 4);
#pragma unroll
  for (int i = 0; i < 8; ++i) {
    int row = mbase + tm * 8 + i;
    if (row < N_NODES) {
      float4 o = {acc[i][0] + bv.x, acc[i][1] + bv.y, acc[i][2] + bv.z, acc[i][3] + bv.w};
      *(float4*)(h + (size_t)row * HID + tn * 4) = o;
    }
  }
}

// ======== edge message (fp32, atomics) ========
__global__ __launch_bounds__(256) void edge_msg_kernel(
    const float* __restrict__ h, const float* __restrict__ ea,
    const int* __restrict__ src, const int* __restrict__ dst,
    const float* __restrict__ ew, const float* __restrict__ eb,
    float* __restrict__ agg) {
  int tid = threadIdx.x;
  int lane = tid & 63;
  int wid = __builtin_amdgcn_readfirstlane(tid >> 6);
  float2 ewreg[32];
#pragma unroll
  for (int k = 0; k < 32; ++k)
    ewreg[k] = *(const float2*)(ew + k * HID + lane * 2);
  float2 ebv = *(const float2*)(eb + lane * 2);
  int e0 = blockIdx.x * 256 + wid * 64;
  for (int i = 0; i < 64; ++i) {
    int e = e0 + i;
    if (e >= N_EDGES) break;
    int s = src[e], d = dst[e];
    float2 acc = ebv;
#pragma unroll
    for (int k = 0; k < 32; ++k) {
      float a = ea[(size_t)e * EDGE_DIM + k];
      acc.x = fmaf(a, ewreg[k].x, acc.x);
      acc.y = fmaf(a, ewreg[k].y, acc.y);
    }
    float2 hv = *(const float2*)(h + (size_t)s * HID + lane * 2);
    float m0 = fmaxf(acc.x + hv.x, 0.f);
    float m1 = fmaxf(acc.y + hv.y, 0.f);
    float* ap = agg + (size_t)d * HID + lane * 2;
    atomicAdd(ap, m0);
    atomicAdd(ap + 1, m1);
  }
}

// ======== node MLP via split-bf16 MFMA ========
// tile: 128 nodes x 128 out; 4 waves each 64x64 (4x4 tiles of 16x16x32)
__global__ __launch_bounds__(256) void mlp_mfma(
    const float* __restrict__ h, const float* __restrict__ agg,
    const unsigned short* __restrict__ wl,  // w1t_hi, w1t_lo, w2t_hi, w2t_lo
    const float* __restrict__ b1, const float* __restrict__ b2,
    float* __restrict__ hout) {
  __shared__ unsigned short lds[40960];  // 80 KB
  unsigned short* sAh = lds;               // [0,4096)
  unsigned short* sAl = lds + 4096;        // [4096,8192)
  unsigned short* sBh = lds + 8192;        // [8192,12288)
  unsigned short* sBl = lds + 12288;       // [12288,16384)
  unsigned short* t1h = lds;               // [0,16384)    phase2
  unsigned short* t1l = lds + 16384;       // [16384,32768)
  unsigned short* sB2h = lds + 32768;      // [32768,36864)
  unsigned short* sB2l = lds + 36864;      // [36864,40960)
  const unsigned short* w1h = wl;
  const unsigned short* w1l = wl + 16384;
  const unsigned short* w2h = wl + 32768;
  const unsigned short* w2l = wl + 49152;
  int tid = threadIdx.x, lane = tid & 63, wave = tid >> 6;
  int wm = wave & 1, wn = wave >> 1;
  int mbase = blockIdx.x * 128;
  const f32x4 zf = {0.f, 0.f, 0.f, 0.f};

  f32x4 acc[4][4];
#pragma unroll
  for (int a = 0; a < 4; ++a)
#pragma unroll
    for (int bq = 0; bq < 4; ++bq) acc[a][bq] = zf;

  for (int c = 0; c < 4; ++c) {
    __syncthreads();
#pragma unroll
    for (int it = 0; it < 4; ++it) {
      int idx = it * 256 + tid;
      int m = idx >> 3, k4 = (idx & 7) * 4;
      int row = mbase + m; if (row >= N_NODES) row = N_NODES - 1;
      size_t g = (size_t)row * HID + c * 32 + k4;
      float4 hv = *(const float4*)(h + g);
      float4 av = *(const float4*)(agg + g);
      float z0 = hv.x + av.x, z1 = hv.y + av.y, z2 = hv.z + av.z, z3 = hv.w + av.w;
      unsigned short h0 = f2bf(z0), h1 = f2bf(z1), h2 = f2bf(z2), h3 = f2bf(z3);
      int slot = ((m >> 4) * 4 + (k4 >> 3)) * 16 + (m & 15);
      int off = slot * 8 + (k4 & 7);
      short4v ph = {(short)h0, (short)h1, (short)h2, (short)h3};
      short4v pl = {(short)f2bf(z0 - bf2f(h0)), (short)f2bf(z1 - bf2f(h1)),
                    (short)f2bf(z2 - bf2f(h2)), (short)f2bf(z3 - bf2f(h3))};
      *(short4v*)(sAh + off) = ph;
      *(short4v*)(sAl + off) = pl;
    }
#pragma unroll
    for (int it = 0; it < 2; ++it) {
      int s = it * 256 + tid;  // 512 slots: [ntile 8][kgrp 4][nrow 16]
      int ntile = s >> 6, kgrp = (s >> 4) & 3, nrow = s & 15;
      int goff = (ntile * 16 + nrow) * 128 + c * 32 + kgrp * 8;
      *(short8*)(sBh + s * 8) = *(const short8*)(w1h + goff);
      *(short8*)(sBl + s * 8) = *(const short8*)(w1l + goff);
    }
    __syncthreads();
    short8 ah[4], al[4], bh[4], bl[4];
#pragma unroll
    for (int mt = 0; mt < 4; ++mt) {
      ah[mt] = *(short8*)(sAh + ((wm * 4 + mt) * 64 + lane) * 8);
      al[mt] = *(short8*)(sAl + ((wm * 4 + mt) * 64 + lane) * 8);
    }
#pragma unroll
    for (int nt = 0; nt < 4; ++nt) {
      bh[nt] = *(short8*)(sBh + ((wn * 4 + nt) * 64 + lane) * 8);
      bl[nt] = *(short8*)(sBl + ((wn * 4 + nt) * 64 + lane) * 8);
    }
#pragma unroll
    for (int mt = 0; mt < 4; ++mt)
#pragma unroll
      for (int nt = 0; nt < 4; ++nt) {
        acc[mt][nt] = MFMA16(ah[mt], bh[nt], acc[mt][nt]);
        acc[mt][nt] = MFMA16(ah[mt], bl[nt], acc[mt][nt]);
        acc[mt][nt] = MFMA16(al[mt], bh[nt], acc[mt][nt]);
      }
  }
  __syncthreads();
  // t1 = relu(acc + b1), split, stored in A-fragment layout [mtile][kgrp16][mrow]x8
  int q = lane >> 4, r = lane & 15;
#pragma unroll
  for (int nt = 0; nt < 4; ++nt) {
    int n = wn * 64 + nt * 16 + r;
    float b1v = b1[n];
    int kgrp = n >> 3, jj = n & 7;
#pragma unroll
    for (int mt = 0; mt < 4; ++mt) {
      int mtg = wm * 4 + mt;
#pragma unroll
      for (int i2 = 0; i2 < 4; ++i2) {
        int mrow = q * 4 + i2;
        float val = fmaxf(acc[mt][nt][i2] + b1v, 0.f);
        unsigned short hi = f2bf(val);
        int idx = ((mtg * 16 + kgrp) * 16 + mrow) * 8 + jj;
        t1h[idx] = hi;
        t1l[idx] = f2bf(val - bf2f(hi));
      }
    }
  }

  f32x4 acc2[4][4];
#pragma unroll
  for (int a = 0; a < 4; ++a)
#pragma unroll
    for (int bq = 0; bq < 4; ++bq) acc2[a][bq] = zf;

  for (int kc = 0; kc < 4; ++kc) {
    __syncthreads();
#pragma unroll
    for (int it = 0; it < 2; ++it) {
      int s = it * 256 + tid;
      int ntile = s >> 6, kgrp = (s >> 4) & 3, nrow = s & 15;
      int goff = (ntile * 16 + nrow) * 128 + kc * 32 + kgrp * 8;
      *(short8*)(sB2h + s * 8) = *(const short8*)(w2h + goff);
      *(short8*)(sB2l + s * 8) = *(const short8*)(w2l + goff);
    }
    __syncthreads();
    short8 ah[4], al[4], bh[4], bl[4];
#pragma unroll
    for (int mt = 0; mt < 4; ++mt) {
      int mtg = wm * 4 + mt;
      int idx = ((mtg * 16 + kc * 4 + q) * 16 + r) * 8;
      ah[mt] = *(short8*)(t1h + idx);
      al[mt] = *(short8*)(t1l + idx);
    }
#pragma unroll
    for (int nt = 0; nt < 4; ++nt) {
      bh[nt] = *(short8*)(sB2h + ((wn * 4 + nt) * 64 + lane) * 8);
      bl[nt] = *(short8*)(sB2l + ((wn * 4 + nt) * 64 + lane) * 8);
    }
#pragma unroll
    for (int mt = 0; mt < 4; ++mt)
#pragma unroll
      for (int nt = 0; nt < 4; ++nt) {
        acc2[mt][nt] = MFMA16(ah[mt], bh[nt], acc2[mt][nt]);
        acc2[mt][nt] = MFMA16(ah[mt], bl[nt], acc2[mt][nt]);
        acc2[mt][nt] = MFMA16(al[mt], bh[nt], acc2[mt][nt]);
      }
  }
  // epilogue: hout = relu(acc2 + b2)
#pragma unroll
  for (int nt = 0; nt < 4; ++nt) {
    int n = wn * 64 + nt * 16 + r;
    float b2v = b2[n];
#pragma unroll
    for (int mt = 0; mt < 4; ++mt) {
      int mtg = wm * 4 + mt;
#pragma unroll
      for (int i2 = 0; i2 < 4; ++i2) {
        int row = mbase + mtg * 16 + q * 4 + i2;
        if (row < N_NODES)
          hout[(size_t)row * HID + n] = fmaxf(acc2[mt][nt][i2] + b2v, 0.f);
      }
    }
  }
}

// ======== classifier via bf16 MFMA: 128 edges x 128, K=288; then x24 ========
__global__ __launch_bounds__(256) void cls_mfma(
    const float* __restrict__ h, const float* __restrict__ ea,
    const int* __restrict__ src, const int* __restrict__ dst,
    const unsigned short* __restrict__ w1t, const unsigned short* __restrict__ w2t,
    const float* __restrict__ b1, const float* __restrict__ b2,
    float* __restrict__ out) {
  __shared__ unsigned short lds[20480];  // 40 KB
  unsigned short* sA = lds;              // [0,4096)
  unsigned short* sB = lds + 4096;       // [4096,8192)
  unsigned short* t1 = lds;              // [0,16384)  phase2
  unsigned short* sB2 = lds + 16384;     // [16384,20480)
  __shared__ int sidx[256];
  int tid = threadIdx.x, lane = tid & 63, wave = tid >> 6;
  int wm = wave & 1, wn = wave >> 1;
  int ebase = blockIdx.x * 128;
  const f32x4 zf = {0.f, 0.f, 0.f, 0.f};

  {
    int e0 = ebase + (tid & 127);
    if (e0 >= N_EDGES) e0 = N_EDGES - 1;
    sidx[tid] = (tid < 128 ? src : dst)[e0];
  }

  f32x4 acc[4][4];
#pragma unroll
  for (int a = 0; a < 4; ++a)
#pragma unroll
    for (int bq = 0; bq < 4; ++bq) acc[a][bq] = zf;

  for (int c = 0; c < 9; ++c) {
    __syncthreads();
#pragma unroll
    for (int it = 0; it < 4; ++it) {
      int idx = it * 256 + tid;
      int m = idx >> 3, k4 = (idx & 7) * 4;
      const float* rp;
      if (c < 4)      rp = h + (size_t)sidx[m] * HID + c * 32 + k4;
      else if (c < 8) rp = h + (size_t)sidx[128 + m] * HID + (c - 4) * 32 + k4;
      else {
        int e8 = ebase + m; if (e8 >= N_EDGES) e8 = N_EDGES - 1;
        rp = ea + (size_t)e8 * EDGE_DIM + k4;
      }
      float4 v = *(const float4*)rp;
      int slot = ((m >> 4) * 4 + (k4 >> 3)) * 16 + (m & 15);
      short4v pk = {(short)f2bf(v.x), (short)f2bf(v.y), (short)f2bf(v.z), (short)f2bf(v.w)};
      *(short4v*)(sA + slot * 8 + (k4 & 7)) = pk;
    }
#pragma unroll
    for (int it = 0; it < 2; ++it) {
      int s = it * 256 + tid;
      int ntile = s >> 6, kgrp = (s >> 4) & 3, nrow = s & 15;
      *(short8*)(sB + s * 8) = *(const short8*)(w1t + (ntile * 16 + nrow) * 288 + c * 32 + kgrp * 8);
    }
    __syncthreads();
    short8 af[4], bfv[4];
#pragma unroll
    for (int mt = 0; mt < 4; ++mt)
      af[mt] = *(short8*)(sA + ((wm * 4 + mt) * 64 + lane) * 8);
#pragma unroll
    for (int nt = 0; nt < 4; ++nt)
      bfv[nt] = *(short8*)(sB + ((wn * 4 + nt) * 64 + lane) * 8);
#pragma unroll
    for (int mt = 0; mt < 4; ++mt)
#pragma unroll
      for (int nt = 0; nt < 4; ++nt)
        acc[mt][nt] = MFMA16(af[mt], bfv[nt], acc[mt][nt]);
  }
  __syncthreads();
  // t1 = relu(acc + b1) -> bf16 A-frag layout
  int q = lane >> 4, r = lane & 15;
#pragma unroll
  for (int nt = 0; nt < 4; ++nt) {
    int n = wn * 64 + nt * 16 + r;
    float b1v = b1[n];
    int kgrp = n >> 3, jj = n & 7;
#pragma unroll
    for (int mt = 0; mt < 4; ++mt) {
      int mtg = wm * 4 + mt;
#pragma unroll
      for (int i2 = 0; i2 < 4; ++i2) {
        int mrow = q * 4 + i2;
        float val = fmaxf(acc[mt][nt][i2] + b1v, 0.f);
        t1[((mtg * 16 + kgrp) * 16 + mrow) * 8 + jj] = f2bf(val);
      }
    }
  }
  // stage full w2t (32x128)
#pragma unroll
  for (int it = 0; it < 2; ++it) {
    int s = it * 256 + tid;  // [ntile 2][kgrp 16][nrow 16]
    int ntile = s >> 8, kgrp = (s >> 4) & 15, nrow = s & 15;
    *(short8*)(sB2 + s * 8) = *(const short8*)(w2t + (ntile * 16 + nrow) * 128 + kgrp * 8);
  }
  __syncthreads();

  f32x4 acc2[2][2];
  acc2[0][0] = zf; acc2[0][1] = zf; acc2[1][0] = zf; acc2[1][1] = zf;
#pragma unroll
  for (int kc = 0; kc < 4; ++kc) {
    short8 a0 = *(short8*)(t1 + (((wave * 2 + 0) * 16 + kc * 4 + q) * 16 + r) * 8);
    short8 a1 = *(short8*)(t1 + (((wave * 2 + 1) * 16 + kc * 4 + q) * 16 + r) * 8);
    short8 b0 = *(short8*)(sB2 + ((0 * 16 + kc * 4 + q) * 16 + r) * 8);
    short8 b1f = *(short8*)(sB2 + ((1 * 16 + kc * 4 + q) * 16 + r) * 8);
    acc2[0][0] = MFMA16(a0, b0, acc2[0][0]);
    acc2[0][1] = MFMA16(a0, b1f, acc2[0][1]);
    acc2[1][0] = MFMA16(a1, b0, acc2[1][0]);
    acc2[1][1] = MFMA16(a1, b1f, acc2[1][1]);
  }
#pragma unroll
  for (int nt2 = 0; nt2 < 2; ++nt2) {
    int n = nt2 * 16 + r;
    float b2v = (n < OUT_DIM) ? b2[n] : 0.f;
#pragma unroll
    for (int mt2 = 0; mt2 < 2; ++mt2) {
      int mtg = wave * 2 + mt2;
#pragma unroll
      for (int i2 = 0; i2 < 4; ++i2) {
        int e = ebase + mtg * 16 + q * 4 + i2;
        if (n < OUT_DIM && e < N_EDGES)
          out[(size_t)e * OUT_DIM + n] = acc2[mt2][nt2][i2] + b2v;
      }
    }
  }
}

extern "C" void kernel_launch(void* const* d_in, const int* in_sizes, int n_in,
                              void* d_out, int out_size, void* d_ws, size_t ws_size,
                              hipStream_t stream) {
  const float* x = (const float*)d_in[0];
  const int* ei = (const int*)d_in[1];
  const float* ea = (const float*)d_in[2];
  const float* lin1_w = (const float*)d_in[3];
  const float* lin1_b = (const float*)d_in[4];
  const int* src = ei;
  const int* dst = ei + N_EDGES;

  const size_t NH = (size_t)N_NODES * HID;
  float* bufA = (float*)d_ws;
  float* bufB = bufA + NH;
  // prepped weights at the END of ws (region ~464 KB, 256B-aligned)
  unsigned short* wbase = (unsigned short*)((((uintptr_t)d_ws + ws_size) - (size_t)W_TOTAL * 2) & ~(uintptr_t)255);

  prep_weights<<<(139264 + 255) / 256, 256, 0, stream>>>(
      (const float*)d_in[23], (const float*)d_in[25],
      (const float*)d_in[7], (const float*)d_in[9],
      (const float*)d_in[13], (const float*)d_in[15],
      (const float*)d_in[19], (const float*)d_in[21], wbase);

  lin1_kernel<<<(N_NODES + 63) / 64, 256, 0, stream>>>(x, lin1_w, lin1_b, bufA);

  float* hcur = bufA;
  float* aux = bufB;
  for (int c = 0; c < 3; ++c) {
    const float* ew = (const float*)d_in[5 + c * 6 + 0];
    const float* eb = (const float*)d_in[5 + c * 6 + 1];
    const float* b1 = (const float*)d_in[5 + c * 6 + 3];
    const float* b2 = (const float*)d_in[5 + c * 6 + 5];
    hipMemsetAsync(aux, 0, NH * sizeof(float), stream);
    edge_msg_kernel<<<(N_EDGES + 255) / 256, 256, 0, stream>>>(
        hcur, ea, src, dst, ew, eb, aux);
    mlp_mfma<<<(N_NODES + 127) / 128, 256, 0, stream>>>(
        hcur, aux, wbase + OFF_LAYER(c), b1, b2, aux);
    float* tmp = hcur; hcur = aux; aux = tmp;
  }

  const float* cb1 = (const float*)d_in[24];
  const float* cb2 = (const float*)d_in[26];
  cls_mfma<<<(N_EDGES + 127) / 128, 256, 0, stream>>>(
      hcur, ea, src, dst, wbase + OFF_CW1T, wbase + OFF_CW2T, cb1, cb2, (float*)d_out);
}

// Round 4
// 1632.506 us; speedup vs baseline: 2.2959x; 1.2412x over previous
//
#include <hip/hip_runtime.h>

#define N_NODES 100000
#define N_EDGES 600000
#define NODE_DIM 64
#define EDGE_DIM 32
#define HID 128
#define OUT_DIM 24

typedef short short8 __attribute__((ext_vector_type(8)));
typedef short short4v __attribute__((ext_vector_type(4)));
typedef float f32x4 __attribute__((ext_vector_type(4)));

#define MFMA16(a, b, c) __builtin_amdgcn_mfma_f32_16x16x32_bf16(a, b, c, 0, 0, 0)

__device__ inline unsigned short f2bf(float f) {
  unsigned u = __float_as_uint(f);
  u += 0x7FFFu + ((u >> 16) & 1u);
  return (unsigned short)(u >> 16);
}
__device__ inline float bf2f(unsigned short b) {
  return __uint_as_float(((unsigned)b) << 16);
}

// ---- prepped weight region layout (ushort units) ----
#define OFF_CW1T 0                       // cls w1^T bf16 [128][288]
#define OFF_CW2T 36864                   // cls w2^T bf16 [32 pad][128]
#define OFF_LAYER(c) (40960 + (c)*65536) // per conv: w1t_hi,w1t_lo,w2t_hi,w2t_lo each [128][128]
#define W_TOTAL 237568

__global__ __launch_bounds__(256) void prep_weights(
    const float* __restrict__ cw1, const float* __restrict__ cw2,
    const float* __restrict__ l0w1, const float* __restrict__ l0w2,
    const float* __restrict__ l1w1, const float* __restrict__ l1w2,
    const float* __restrict__ l2w1, const float* __restrict__ l2w2,
    unsigned short* __restrict__ wb) {
  int i = blockIdx.x * 256 + threadIdx.x;
  if (i < 36864) {                       // cls w1t[n][k] = cw1[k][n]
    int n = i / 288, k = i % 288;
    wb[OFF_CW1T + i] = f2bf(cw1[k * 128 + n]);
  }
  int j = i - 36864;
  if (j >= 0 && j < 4096) {              // cls w2t[n][k], n padded to 32
    int n = j / 128, k = j % 128;
    wb[OFF_CW2T + j] = f2bf(n < 24 ? cw2[k * 24 + n] : 0.f);
  }
  int t = i - 40960;
  if (t >= 0 && t < 3 * 32768) {         // conv layers, split hi/lo
    int c = t / 32768, u = t % 32768;
    const float* w = (u < 16384) ? (c == 0 ? l0w1 : c == 1 ? l1w1 : l2w1)
                                 : (c == 0 ? l0w2 : c == 1 ? l1w2 : l2w2);
    int v = u & 16383;
    int n = v >> 7, k = v & 127;
    float val = w[k * 128 + n];
    unsigned short hi = f2bf(val);
    unsigned short lo = f2bf(val - bf2f(hi));
    int base = OFF_LAYER(c) + (u < 16384 ? 0 : 32768);
    wb[base + v] = hi;
    wb[base + 16384 + v] = lo;
  }
}

// ================= lin1: h = x @ w + b  (K=64, fp32) =================
__global__ __launch_bounds__(256) void lin1_kernel(
    const float* __restrict__ x, const float* __restrict__ w,
    const float* __restrict__ b, float* __restrict__ h) {
  __shared__ float4 smem4[3072];
  float* sA = (float*)smem4;
  float* sB = (float*)smem4 + 4096;
  int tid = threadIdx.x;
  int tn = tid & 31, tm = tid >> 5;
  int mbase = blockIdx.x * 64;

  for (int i = tid; i < 1024; i += 256) {
    int m = i & 63, k4 = (i >> 6) << 2;
    int row = mbase + m; if (row >= N_NODES) row = N_NODES - 1;
    float4 v = *(const float4*)(x + (size_t)row * NODE_DIM + k4);
    sA[(k4 + 0) * 64 + m] = v.x; sA[(k4 + 1) * 64 + m] = v.y;
    sA[(k4 + 2) * 64 + m] = v.z; sA[(k4 + 3) * 64 + m] = v.w;
  }
  for (int i = tid; i < 2048; i += 256)
    *(float4*)&sB[i * 4] = ((const float4*)w)[i];
  __syncthreads();

  float acc[8][4] = {};
#pragma unroll 8
  for (int k = 0; k < 64; ++k) {
    float4 a0 = *(float4*)&sA[k * 64 + tm * 8];
    float4 a1 = *(float4*)&sA[k * 64 + tm * 8 + 4];
    float4 bv = *(float4*)&sB[k * 128 + tn * 4];
    float av[8] = {a0.x, a0.y, a0.z, a0.w, a1.x, a1.y, a1.z, a1.w};
    float bb[4] = {bv.x, bv.y, bv.z, bv.w};
#pragma unroll
    for (int i = 0; i < 8; ++i)
#pragma unroll
      for (int jj = 0; jj < 4; ++jj) acc[i][jj] = fmaf(av[i], bb[jj], acc[i][jj]);
  }
  float4 bv = *(const float4*)(b + tn * 4);
#pragma unroll
  for (int i = 0; i < 8; ++i) {
    int row = mbase + tm * 8 + i;
    if (row < N_NODES) {
      float4 o = {acc[i][0] + bv.x, acc[i][1] + bv.y, acc[i][2] + bv.z, acc[i][3] + bv.w};
      *(float4*)(h + (size_t)row * HID + tn * 4) = o;
    }
  }
}

// ======================= CSR build =======================
__global__ __launch_bounds__(256) void hist_kernel(
    const int* __restrict__ dst, int* __restrict__ counts) {
  int e = blockIdx.x * 256 + threadIdx.x;
  if (e < N_EDGES) atomicAdd(&counts[dst[e]], 1);
}

#define SCAN_BLK 98  // ceil(100000/1024)
__global__ __launch_bounds__(256) void scan_partial(
    const int* __restrict__ cnt, int* __restrict__ partial) {
  __shared__ int sdata[256];
  int b = blockIdx.x, t = threadIdx.x;
  int sum = 0;
  for (int i = t; i < 1024; i += 256) {
    int idx = b * 1024 + i;
    sum += (idx < N_NODES) ? cnt[idx] : 0;
  }
  sdata[t] = sum; __syncthreads();
  for (int s = 128; s > 0; s >>= 1) {
    if (t < s) sdata[t] += sdata[t + s];
    __syncthreads();
  }
  if (t == 0) partial[b] = sdata[0];
}

__global__ void scan_sums(const int* __restrict__ partial,
                          int* __restrict__ partialScan, int* __restrict__ rowptr) {
  if (threadIdx.x == 0) {
    int acc = 0;
    for (int i = 0; i < SCAN_BLK; ++i) { partialScan[i] = acc; acc += partial[i]; }
    rowptr[N_NODES] = acc;
  }
}

__global__ __launch_bounds__(256) void scan_final(
    const int* __restrict__ cnt, const int* __restrict__ partialScan,
    int* __restrict__ rowptr, int* __restrict__ cur) {
  __shared__ int sdata[256];
  int b = blockIdx.x, t = threadIdx.x;
  int i0 = b * 1024 + t * 4;
  int c[4]; int s = 0;
#pragma unroll
  for (int j = 0; j < 4; ++j) {
    c[j] = (i0 + j < N_NODES) ? cnt[i0 + j] : 0;
    s += c[j];
  }
  sdata[t] = s; __syncthreads();
  for (int d = 1; d < 256; d <<= 1) {
    int u = (t >= d) ? sdata[t - d] : 0;
    __syncthreads();
    sdata[t] += u;
    __syncthreads();
  }
  int off = sdata[t] - s + partialScan[b];
#pragma unroll
  for (int j = 0; j < 4; ++j) {
    int idx = i0 + j;
    if (idx < N_NODES) { rowptr[idx] = off; cur[idx] = off; off += c[j]; }
  }
}

__global__ __launch_bounds__(256) void scatter_kernel(
    const int* __restrict__ dst, int* __restrict__ cur, int* __restrict__ perm) {
  int e = blockIdx.x * 256 + threadIdx.x;
  if (e < N_EDGES) {
    int slot = atomicAdd(&cur[dst[e]], 1);
    perm[slot] = e;
  }
}

// ======== aggregation: one wave per dst node, no atomics ========
__global__ __launch_bounds__(256) void agg_gather_kernel(
    const float* __restrict__ h, const float* __restrict__ ea,
    const int* __restrict__ srcv, const int* __restrict__ perm,
    const int* __restrict__ rowptr,
    const float* __restrict__ ew, const float* __restrict__ eb,
    float* __restrict__ agg) {
  int tid = threadIdx.x, lane = tid & 63;
  int wid = blockIdx.x * 4 + (tid >> 6);
  int nwaves = gridDim.x * 4;
  float2 ewreg[32];
#pragma unroll
  for (int k = 0; k < 32; ++k)
    ewreg[k] = *(const float2*)(ew + k * HID + lane * 2);
  float2 ebv = *(const float2*)(eb + lane * 2);

  for (int node = wid; node < N_NODES; node += nwaves) {
    int beg = rowptr[node], end = rowptr[node + 1];
    float2 acc = {0.f, 0.f};
    for (int i = beg; i < end; ++i) {
      int e = perm[i];
      int s = srcv[e];
      const float4* ear = (const float4*)(ea + (size_t)e * EDGE_DIM);
      float2 macc = ebv;
#pragma unroll
      for (int k4 = 0; k4 < 8; ++k4) {
        float4 a = ear[k4];
        macc.x = fmaf(a.x, ewreg[k4 * 4 + 0].x, macc.x);
        macc.y = fmaf(a.x, ewreg[k4 * 4 + 0].y, macc.y);
        macc.x = fmaf(a.y, ewreg[k4 * 4 + 1].x, macc.x);
        macc.y = fmaf(a.y, ewreg[k4 * 4 + 1].y, macc.y);
        macc.x = fmaf(a.z, ewreg[k4 * 4 + 2].x, macc.x);
        macc.y = fmaf(a.z, ewreg[k4 * 4 + 2].y, macc.y);
        macc.x = fmaf(a.w, ewreg[k4 * 4 + 3].x, macc.x);
        macc.y = fmaf(a.w, ewreg[k4 * 4 + 3].y, macc.y);
      }
      float2 hv = *(const float2*)(h + (size_t)s * HID + lane * 2);
      acc.x += fmaxf(macc.x + hv.x, 0.f);
      acc.y += fmaxf(macc.y + hv.y, 0.f);
    }
    *(float2*)(agg + (size_t)node * HID + lane * 2) = acc;
  }
}

// ======== node MLP via split-bf16 MFMA ========
__global__ __launch_bounds__(256) void mlp_mfma(
    const float* __restrict__ h, const float* __restrict__ agg,
    const unsigned short* __restrict__ wl,
    const float* __restrict__ b1, const float* __restrict__ b2,
    float* __restrict__ hout) {
  __shared__ unsigned short lds[40960];  // 80 KB
  unsigned short* sAh = lds;
  unsigned short* sAl = lds + 4096;
  unsigned short* sBh = lds + 8192;
  unsigned short* sBl = lds + 12288;
  unsigned short* t1h = lds;
  unsigned short* t1l = lds + 16384;
  unsigned short* sB2h = lds + 32768;
  unsigned short* sB2l = lds + 36864;
  const unsigned short* w1h = wl;
  const unsigned short* w1l = wl + 16384;
  const unsigned short* w2h = wl + 32768;
  const unsigned short* w2l = wl + 49152;
  int tid = threadIdx.x, lane = tid & 63, wave = tid >> 6;
  int wm = wave & 1, wn = wave >> 1;
  int mbase = blockIdx.x * 128;
  const f32x4 zf = {0.f, 0.f, 0.f, 0.f};

  f32x4 acc[4][4];
#pragma unroll
  for (int a = 0; a < 4; ++a)
#pragma unroll
    for (int bq = 0; bq < 4; ++bq) acc[a][bq] = zf;

  for (int c = 0; c < 4; ++c) {
    __syncthreads();
#pragma unroll
    for (int it = 0; it < 4; ++it) {
      int idx = it * 256 + tid;
      int m = idx >> 3, k4 = (idx & 7) * 4;
      int row = mbase + m; if (row >= N_NODES) row = N_NODES - 1;
      size_t g = (size_t)row * HID + c * 32 + k4;
      float4 hv = *(const float4*)(h + g);
      float4 av = *(const float4*)(agg + g);
      float z0 = hv.x + av.x, z1 = hv.y + av.y, z2 = hv.z + av.z, z3 = hv.w + av.w;
      unsigned short h0 = f2bf(z0), h1 = f2bf(z1), h2 = f2bf(z2), h3 = f2bf(z3);
      int slot = ((m >> 4) * 4 + (k4 >> 3)) * 16 + (m & 15);
      int off = slot * 8 + (k4 & 7);
      short4v ph = {(short)h0, (short)h1, (short)h2, (short)h3};
      short4v pl = {(short)f2bf(z0 - bf2f(h0)), (short)f2bf(z1 - bf2f(h1)),
                    (short)f2bf(z2 - bf2f(h2)), (short)f2bf(z3 - bf2f(h3))};
      *(short4v*)(sAh + off) = ph;
      *(short4v*)(sAl + off) = pl;
    }
#pragma unroll
    for (int it = 0; it < 2; ++it) {
      int s = it * 256 + tid;
      int ntile = s >> 6, kgrp = (s >> 4) & 3, nrow = s & 15;
      int goff = (ntile * 16 + nrow) * 128 + c * 32 + kgrp * 8;
      *(short8*)(sBh + s * 8) = *(const short8*)(w1h + goff);
      *(short8*)(sBl + s * 8) = *(const short8*)(w1l + goff);
    }
    __syncthreads();
    short8 ah[4], al[4], bh[4], bl[4];
#pragma unroll
    for (int mt = 0; mt < 4; ++mt) {
      ah[mt] = *(short8*)(sAh + ((wm * 4 + mt) * 64 + lane) * 8);
      al[mt] = *(short8*)(sAl + ((wm * 4 + mt) * 64 + lane) * 8);
    }
#pragma unroll
    for (int nt = 0; nt < 4; ++nt) {
      bh[nt] = *(short8*)(sBh + ((wn * 4 + nt) * 64 + lane) * 8);
      bl[nt] = *(short8*)(sBl + ((wn * 4 + nt) * 64 + lane) * 8);
    }
#pragma unroll
    for (int mt = 0; mt < 4; ++mt)
#pragma unroll
      for (int nt = 0; nt < 4; ++nt) {
        acc[mt][nt] = MFMA16(ah[mt], bh[nt], acc[mt][nt]);
        acc[mt][nt] = MFMA16(ah[mt], bl[nt], acc[mt][nt]);
        acc[mt][nt] = MFMA16(al[mt], bh[nt], acc[mt][nt]);
      }
  }
  __syncthreads();
  int q = lane >> 4, r = lane & 15;
#pragma unroll
  for (int nt = 0; nt < 4; ++nt) {
    int n = wn * 64 + nt * 16 + r;
    float b1v = b1[n];
    int kgrp = n >> 3, jj = n & 7;
#pragma unroll
    for (int mt = 0; mt < 4; ++mt) {
      int mtg = wm * 4 + mt;
#pragma unroll
      for (int i2 = 0; i2 < 4; ++i2) {
        int mrow = q * 4 + i2;
        float val = fmaxf(acc[mt][nt][i2] + b1v, 0.f);
        unsigned short hi = f2bf(val);
        int idx = ((mtg * 16 + kgrp) * 16 + mrow) * 8 + jj;
        t1h[idx] = hi;
        t1l[idx] = f2bf(val - bf2f(hi));
      }
    }
  }

  f32x4 acc2[4][4];
#pragma unroll
  for (int a = 0; a < 4; ++a)
#pragma unroll
    for (int bq = 0; bq < 4; ++bq) acc2[a][bq] = zf;

  for (int kc = 0; kc < 4; ++kc) {
    __syncthreads();
#pragma unroll
    for (int it = 0; it < 2; ++it) {
      int s = it * 256 + tid;
      int ntile = s >> 6, kgrp = (s >> 4) & 3, nrow = s & 15;
      int goff = (ntile * 16 + nrow) * 128 + kc * 32 + kgrp * 8;
      *(short8*)(sB2h + s * 8) = *(const short8*)(w2h + goff);
      *(short8*)(sB2l + s * 8) = *(const short8*)(w2l + goff);
    }
    __syncthreads();
    short8 ah[4], al[4], bh[4], bl[4];
#pragma unroll
    for (int mt = 0; mt < 4; ++mt) {
      int mtg = wm * 4 + mt;
      int idx = ((mtg * 16 + kc * 4 + q) * 16 + r) * 8;
      ah[mt] = *(short8*)(t1h + idx);
      al[mt] = *(short8*)(t1l + idx);
    }
#pragma unroll
    for (int nt = 0; nt < 4; ++nt) {
      bh[nt] = *(short8*)(sB2h + ((wn * 4 + nt) * 64 + lane) * 8);
      bl[nt] = *(short8*)(sB2l + ((wn * 4 + nt) * 64 + lane) * 8);
    }
#pragma unroll
    for (int mt = 0; mt < 4; ++mt)
#pragma unroll
      for (int nt = 0; nt < 4; ++nt) {
        acc2[mt][nt] = MFMA16(ah[mt], bh[nt], acc2[mt][nt]);
        acc2[mt][nt] = MFMA16(ah[mt], bl[nt], acc2[mt][nt]);
        acc2[mt][nt] = MFMA16(al[mt], bh[nt], acc2[mt][nt]);
      }
  }
#pragma unroll
  for (int nt = 0; nt < 4; ++nt) {
    int n = wn * 64 + nt * 16 + r;
    float b2v = b2[n];
#pragma unroll
    for (int mt = 0; mt < 4; ++mt) {
      int mtg = wm * 4 + mt;
#pragma unroll
      for (int i2 = 0; i2 < 4; ++i2) {
        int row = mbase + mtg * 16 + q * 4 + i2;
        if (row < N_NODES)
          hout[(size_t)row * HID + n] = fmaxf(acc2[mt][nt][i2] + b2v, 0.f);
      }
    }
  }
}

// ======== classifier via bf16 MFMA ========
__global__ __launch_bounds__(256) void cls_mfma(
    const float* __restrict__ h, const float* __restrict__ ea,
    const int* __restrict__ src, const int* __restrict__ dst,
    const unsigned short* __restrict__ w1t, const unsigned short* __restrict__ w2t,
    const float* __restrict__ b1, const float* __restrict__ b2,
    float* __restrict__ out) {
  __shared__ unsigned short lds[20480];  // 40 KB
  unsigned short* sA = lds;
  unsigned short* sB = lds + 4096;
  unsigned short* t1 = lds;
  unsigned short* sB2 = lds + 16384;
  __shared__ int sidx[256];
  int tid = threadIdx.x, lane = tid & 63, wave = tid >> 6;
  int wm = wave & 1, wn = wave >> 1;
  int ebase = blockIdx.x * 128;
  const f32x4 zf = {0.f, 0.f, 0.f, 0.f};

  {
    int e0 = ebase + (tid & 127);
    if (e0 >= N_EDGES) e0 = N_EDGES - 1;
    sidx[tid] = (tid < 128 ? src : dst)[e0];
  }

  f32x4 acc[4][4];
#pragma unroll
  for (int a = 0; a < 4; ++a)
#pragma unroll
    for (int bq = 0; bq < 4; ++bq) acc[a][bq] = zf;

  for (int c = 0; c < 9; ++c) {
    __syncthreads();
#pragma unroll
    for (int it = 0; it < 4; ++it) {
      int idx = it * 256 + tid;
      int m = idx >> 3, k4 = (idx & 7) * 4;
      const float* rp;
      if (c < 4)      rp = h + (size_t)sidx[m] * HID + c * 32 + k4;
      else if (c < 8) rp = h + (size_t)sidx[128 + m] * HID + (c - 4) * 32 + k4;
      else {
        int e8 = ebase + m; if (e8 >= N_EDGES) e8 = N_EDGES - 1;
        rp = ea + (size_t)e8 * EDGE_DIM + k4;
      }
      float4 v = *(const float4*)rp;
      int slot = ((m >> 4) * 4 + (k4 >> 3)) * 16 + (m & 15);
      short4v pk = {(short)f2bf(v.x), (short)f2bf(v.y), (short)f2bf(v.z), (short)f2bf(v.w)};
      *(short4v*)(sA + slot * 8 + (k4 & 7)) = pk;
    }
#pragma unroll
    for (int it = 0; it < 2; ++it) {
      int s = it * 256 + tid;
      int ntile = s >> 6, kgrp = (s >> 4) & 3, nrow = s & 15;
      *(short8*)(sB + s * 8) = *(const short8*)(w1t + (ntile * 16 + nrow) * 288 + c * 32 + kgrp * 8);
    }
    __syncthreads();
    short8 af[4], bfv[4];
#pragma unroll
    for (int mt = 0; mt < 4; ++mt)
      af[mt] = *(short8*)(sA + ((wm * 4 + mt) * 64 + lane) * 8);
#pragma unroll
    for (int nt = 0; nt < 4; ++nt)
      bfv[nt] = *(short8*)(sB + ((wn * 4 + nt) * 64 + lane) * 8);
#pragma unroll
    for (int mt = 0; mt < 4; ++mt)
#pragma unroll
      for (int nt = 0; nt < 4; ++nt)
        acc[mt][nt] = MFMA16(af[mt], bfv[nt], acc[mt][nt]);
  }
  __syncthreads();
  int q = lane >> 4, r = lane & 15;
#pragma unroll
  for (int nt = 0; nt < 4; ++nt) {
    int n = wn * 64 + nt * 16 + r;
    float b1v = b1[n];
    int kgrp = n >> 3, jj = n & 7;
#pragma unroll
    for (int mt = 0; mt < 4; ++mt) {
      int mtg = wm * 4 + mt;
#pragma unroll
      for (int i2 = 0; i2 < 4; ++i2) {
        int mrow = q * 4 + i2;
        float val = fmaxf(acc[mt][nt][i2] + b1v, 0.f);
        t1[((mtg * 16 + kgrp) * 16 + mrow) * 8 + jj] = f2bf(val);
      }
    }
  }
#pragma unroll
  for (int it = 0; it < 2; ++it) {
    int s = it * 256 + tid;
    int ntile = s >> 8, kgrp = (s >> 4) & 15, nrow = s & 15;
    *(short8*)(sB2 + s * 8) = *(const short8*)(w2t + (ntile * 16 + nrow) * 128 + kgrp * 8);
  }
  __syncthreads();

  f32x4 acc2[2][2];
  acc2[0][0] = zf; acc2[0][1] = zf; acc2[1][0] = zf; acc2[1][1] = zf;
#pragma unroll
  for (int kc = 0; kc < 4; ++kc) {
    short8 a0 = *(short8*)(t1 + (((wave * 2 + 0) * 16 + kc * 4 + q) * 16 + r) * 8);
    short8 a1 = *(short8*)(t1 + (((wave * 2 + 1) * 16 + kc * 4 + q) * 16 + r) * 8);
    short8 b0 = *(short8*)(sB2 + ((0 * 16 + kc * 4 + q) * 16 + r) * 8);
    short8 b1f = *(short8*)(sB2 + ((1 * 16 + kc * 4 + q) * 16 + r) * 8);
    acc2[0][0] = MFMA16(a0, b0, acc2[0][0]);
    acc2[0][1] = MFMA16(a0, b1f, acc2[0][1]);
    acc2[1][0] = MFMA16(a1, b0, acc2[1][0]);
    acc2[1][1] = MFMA16(a1, b1f, acc2[1][1]);
  }
#pragma unroll
  for (int nt2 = 0; nt2 < 2; ++nt2) {
    int n = nt2 * 16 + r;
    float b2v = (n < OUT_DIM) ? b2[n] : 0.f;
#pragma unroll
    for (int mt2 = 0; mt2 < 2; ++mt2) {
      int mtg = wave * 2 + mt2;
#pragma unroll
      for (int i2 = 0; i2 < 4; ++i2) {
        int e = ebase + mtg * 16 + q * 4 + i2;
        if (n < OUT_DIM && e < N_EDGES)
          out[(size_t)e * OUT_DIM + n] = acc2[mt2][nt2][i2] + b2v;
      }
    }
  }
}

extern "C" void kernel_launch(void* const* d_in, const int* in_sizes, int n_in,
                              void* d_out, int out_size, void* d_ws, size_t ws_size,
                              hipStream_t stream) {
  const float* x = (const float*)d_in[0];
  const int* ei = (const int*)d_in[1];
  const float* ea = (const float*)d_in[2];
  const float* lin1_w = (const float*)d_in[3];
  const float* lin1_b = (const float*)d_in[4];
  const int* src = ei;
  const int* dst = ei + N_EDGES;

  const size_t NH = (size_t)N_NODES * HID;
  float* bufA = (float*)d_ws;
  float* bufB = bufA + NH;
  // graph region after bufB (~3.6 MB)
  int* ibase = (int*)(bufB + NH);
  int* rowptr = ibase;                 // N_NODES+1
  int* cur = ibase + 100004;           // N_NODES
  int* counts = ibase + 200004;        // N_NODES
  int* perm = ibase + 300004;          // N_EDGES
  int* partial = ibase + 900004;       // 128
  int* partialScan = ibase + 900132;   // 128
  // prepped weights at the END of ws
  unsigned short* wbase = (unsigned short*)((((uintptr_t)d_ws + ws_size) - (size_t)W_TOTAL * 2) & ~(uintptr_t)255);

  prep_weights<<<(139264 + 255) / 256, 256, 0, stream>>>(
      (const float*)d_in[23], (const float*)d_in[25],
      (const float*)d_in[7], (const float*)d_in[9],
      (const float*)d_in[13], (const float*)d_in[15],
      (const float*)d_in[19], (const float*)d_in[21], wbase);

  lin1_kernel<<<(N_NODES + 63) / 64, 256, 0, stream>>>(x, lin1_w, lin1_b, bufA);

  // ---- CSR build (once; shared by all 3 layers) ----
  hipMemsetAsync(counts, 0, N_NODES * sizeof(int), stream);
  hist_kernel<<<(N_EDGES + 255) / 256, 256, 0, stream>>>(dst, counts);
  scan_partial<<<SCAN_BLK, 256, 0, stream>>>(counts, partial);
  scan_sums<<<1, 64, 0, stream>>>(partial, partialScan, rowptr);
  scan_final<<<SCAN_BLK, 256, 0, stream>>>(counts, partialScan, rowptr, cur);
  scatter_kernel<<<(N_EDGES + 255) / 256, 256, 0, stream>>>(dst, cur, perm);

  float* hcur = bufA;
  float* aux = bufB;
  for (int c = 0; c < 3; ++c) {
    const float* ew = (const float*)d_in[5 + c * 6 + 0];
    const float* eb = (const float*)d_in[5 + c * 6 + 1];
    const float* b1 = (const float*)d_in[5 + c * 6 + 3];
    const float* b2 = (const float*)d_in[5 + c * 6 + 5];
    agg_gather_kernel<<<1280, 256, 0, stream>>>(
        hcur, ea, src, perm, rowptr, ew, eb, aux);
    mlp_mfma<<<(N_NODES + 127) / 128, 256, 0, stream>>>(
        hcur, aux, wbase + OFF_LAYER(c), b1, b2, aux);
    float* tmp = hcur; hcur = aux; aux = tmp;
  }

  const float* cb1 = (const float*)d_in[24];
  const float* cb2 = (const float*)d_in[26];
  cls_mfma<<<(N_EDGES + 127) / 128, 256, 0, stream>>>(
      hcur, ea, src, dst, wbase + OFF_CW1T, wbase + OFF_CW2T, cb1, cb2, (float*)d_out);
}